// Round 7
// baseline (373.612 us; speedup 1.0000x reference)
//
#include <hip/hip_runtime.h>
#include <hip/hip_bf16.h>
#include <stdint.h>

#define DIM 512
#define NROWS 1024
#define NCLS 70722
#define NC16 4421                   // ceil(70722/16) 16-class groups
// 277 c-tiles of 256 cols; 32 c-groups: cgrp<21 own 9 tiles, else 8 (stride-32)

typedef float floatx4 __attribute__((ext_vector_type(4)));

// pack 4 floats -> 4 OCP e4m3 bytes (HW cvt, RNE+sat)
__device__ __forceinline__ unsigned pk4_fp8(float a, float b, float c, float d) {
    unsigned v = 0;
    v = __builtin_amdgcn_cvt_pk_fp8_f32(a, b, v, false);  // low 16 bits
    v = __builtin_amdgcn_cvt_pk_fp8_f32(c, d, v, true);   // high 16 bits
    return v;
}

__device__ __forceinline__ float wave_reduce_sum(float s) {
    #pragma unroll
    for (int m = 1; m < 64; m <<= 1) s += __shfl_xor(s, m);
    return s;
}

// --- kernel 1: fused prep, fragment-transposed outputs -----------------------
// WT layout: 8B k-slot j of class r: WT[(r>>4)*8192 + j*128 + (r&15)*8].
// blocks [0,256):  x rows (wave-per-row) -> AnT (same layout), rownorm,
//                  coslab, rowsum=0; block 0 also zeroes the done counter.
// blocks [256,..): one 16-class group per block; 4 waves x 4 rows wave-per-row
//                  compute -> LDS tile -> one coalesced 8KB transposed burst.
__global__ __launch_bounds__(256) void prep_kernel(
        const float* __restrict__ x, const float* __restrict__ W,
        const int* __restrict__ labels,
        uint8_t* __restrict__ AnT, uint8_t* __restrict__ WT,
        float* __restrict__ rownorm, float* __restrict__ coslab,
        float* __restrict__ rowsum, int* __restrict__ done) {
    __shared__ uint8_t lds[16 * 520];   // 520B row stride: conflict-free transpose
    int b = blockIdx.x;
    int wv = threadIdx.x >> 6, lane = threadIdx.x & 63;
    if (b < NROWS / 4) {
        if (b == 0 && threadIdx.x == 0) *done = 0;
        if (threadIdx.x < 4) rowsum[b * 4 + threadIdx.x] = 0.0f;
        int row = b * 4 + wv;
        int lab = labels[row];
        const float4* xs = (const float4*)(x + (size_t)row * DIM);
        const float4* ws = (const float4*)(W + (size_t)lab * DIM);
        float4 xa = xs[lane * 2], xb = xs[lane * 2 + 1];
        float4 wa = ws[lane * 2], wb = ws[lane * 2 + 1];
        float dxx = xa.x*xa.x + xa.y*xa.y + xa.z*xa.z + xa.w*xa.w
                  + xb.x*xb.x + xb.y*xb.y + xb.z*xb.z + xb.w*xb.w;
        float dww = wa.x*wa.x + wa.y*wa.y + wa.z*wa.z + wa.w*wa.w
                  + wb.x*wb.x + wb.y*wb.y + wb.z*wb.z + wb.w*wb.w;
        float dxw = xa.x*wa.x + xa.y*wa.y + xa.z*wa.z + xa.w*wa.w
                  + xb.x*wb.x + xb.y*wb.y + xb.z*wb.z + xb.w*wb.w;
        dxx = wave_reduce_sum(dxx);
        dww = wave_reduce_sum(dww);
        dxw = wave_reduce_sum(dxw);
        float norm = sqrtf(dxx);
        float s16 = 16.0f / fmaxf(norm, 1e-12f);
        uint2 p;
        p.x = pk4_fp8(xa.x*s16, xa.y*s16, xa.z*s16, xa.w*s16);
        p.y = pk4_fp8(xb.x*s16, xb.y*s16, xb.z*s16, xb.w*s16);
        *(uint2*)(AnT + (size_t)(row >> 4) * 8192 + lane * 128 + (row & 15) * 8) = p;
        if (lane == 0) {
            rownorm[row] = norm;
            coslab[row]  = dxw / (fmaxf(norm, 1e-12f) * fmaxf(sqrtf(dww), 1e-12f));
        }
    } else {
        int g = b - NROWS / 4;              // 16-class group
        float4 va[4], vb[4];
        #pragma unroll
        for (int j = 0; j < 4; ++j) {
            int c = g * 16 + wv * 4 + j;
            va[j] = make_float4(0.f, 0.f, 0.f, 0.f);
            vb[j] = make_float4(0.f, 0.f, 0.f, 0.f);
            if (c < NCLS) {
                const float4* src = (const float4*)(W + (size_t)c * DIM);
                va[j] = src[lane * 2]; vb[j] = src[lane * 2 + 1];
            }
        }
        #pragma unroll
        for (int j = 0; j < 4; ++j) {
            float ss = va[j].x*va[j].x + va[j].y*va[j].y + va[j].z*va[j].z + va[j].w*va[j].w
                     + vb[j].x*vb[j].x + vb[j].y*vb[j].y + vb[j].z*vb[j].z + vb[j].w*vb[j].w;
            ss = wave_reduce_sum(ss);
            float s16 = 16.0f / fmaxf(sqrtf(ss), 1e-12f);
            uint2 p;
            p.x = pk4_fp8(va[j].x*s16, va[j].y*s16, va[j].z*s16, va[j].w*s16);
            p.y = pk4_fp8(vb[j].x*s16, vb[j].y*s16, vb[j].z*s16, vb[j].w*s16);
            int r = wv * 4 + j;
            *(uint2*)(&lds[r * 520 + lane * 8]) = p;
        }
        __syncthreads();
        // transposed burst: thread t writes out bytes [32t,32t+32) of the 8KB
        // group; out byte 8v maps to (j=v>>4, r=v&15) = lds[r*520 + j*8]
        int t = threadIdx.x;
        uint2 v0 = *(const uint2*)&lds[((4*t+0) & 15) * 520 + ((4*t+0) >> 4) * 8];
        uint2 v1 = *(const uint2*)&lds[((4*t+1) & 15) * 520 + ((4*t+1) >> 4) * 8];
        uint2 v2 = *(const uint2*)&lds[((4*t+2) & 15) * 520 + ((4*t+2) >> 4) * 8];
        uint2 v3 = *(const uint2*)&lds[((4*t+3) & 15) * 520 + ((4*t+3) >> 4) * 8];
        uint4 q0, q1;
        q0.x = v0.x; q0.y = v0.y; q0.z = v1.x; q0.w = v1.y;
        q1.x = v2.x; q1.y = v2.y; q1.z = v3.x; q1.w = v3.y;
        uint8_t* dst = WT + (size_t)g * 8192 + t * 32;
        *(uint4*)dst        = q0;
        *(uint4*)(dst + 16) = q1;
    }
}

// --- kernel 2: zero-LDS register GEMM, depth-1 B-pipeline + fused finalize ---
// 256 blocks (8 mgrp x 32 cgrp), 512 thr, wave = 64M x 64C. A fragments for
// ALL of K register-resident (af[4][16]). Per kb: LOADBG(next) issued BEFORE
// the 64-MFMA cluster so the wave's own loads hide under its MFMA issue;
// next c-tile's kb0 prefetched under the epilogue. No LDS/barriers in loop.
// Last block (device-scope counter) runs the fused finalize.
__global__ __launch_bounds__(512, 2) void gemm8_kernel(
        const uint8_t* __restrict__ AnT, const uint8_t* __restrict__ WT,
        float* __restrict__ rowsum, const float* __restrict__ coslab,
        const float* __restrict__ rownorm, float* __restrict__ out,
        int* __restrict__ done) {
    __shared__ float red[128];
    __shared__ float fpart[8];
    __shared__ float fbc[2];
    __shared__ int lastBlk;
    int b = blockIdx.x;
    int mgrp = b >> 5, cgrp = b & 31;
    int tid = threadIdx.x, lane = tid & 63, wv = tid >> 6;

    int wm = (wv >> 2) * 64, wn = (wv & 3) * 64;   // wave = 64M x 64C
    int fr = lane & 15, fq = lane >> 4;

    // ---- A fragments for all of K: 64 coalesced 512B wave-loads
    long af[4][16];
    const uint8_t* ab = AnT + (size_t)(mgrp * 8 + (wm >> 4)) * 8192 + fq * 128 + fr * 8;
    #pragma unroll
    for (int m = 0; m < 4; ++m)
        #pragma unroll
        for (int ksl = 0; ksl < 16; ++ksl)
            af[m][ksl] = *(const long*)(ab + m * 8192 + ksl * 512);

    if (tid < 128) red[tid] = 0.0f;
    __syncthreads();

    const floatx4 vzero = {0.0f, 0.0f, 0.0f, 0.0f};
    floatx4 acc[4][4] = {};
    long bgA[4][4], bgB[4][4];
    const uint8_t* bb[4];

#define SETBB(cc) do { \
        _Pragma("unroll") \
        for (int n = 0; n < 4; ++n) { \
            int g = min((cc) * 16 + (wn >> 4) + n, NC16 - 1); \
            bb[n] = WT + (size_t)g * 8192 + fq * 128 + fr * 8; \
        } } while (0)

#define LOADBG(BG, kb) do { \
        _Pragma("unroll") \
        for (int n = 0; n < 4; ++n) \
            _Pragma("unroll") \
            for (int ks = 0; ks < 4; ++ks) \
                BG[n][ks] = *(const long*)(bb[n] + (kb) * 2048 + ks * 512); \
    } while (0)

#define MFMA64(kb, BG) do { \
        __builtin_amdgcn_s_setprio(1); \
        _Pragma("unroll") \
        for (int ks = 0; ks < 4; ++ks) \
            _Pragma("unroll") \
            for (int m = 0; m < 4; ++m) \
                _Pragma("unroll") \
                for (int n = 0; n < 4; ++n) \
                    acc[m][n] = __builtin_amdgcn_mfma_f32_16x16x32_fp8_fp8( \
                        af[m][(kb) * 4 + ks], BG[n][ks], acc[m][n], 0, 0, 0); \
        __builtin_amdgcn_s_setprio(0); \
    } while (0)

    int nct = (cgrp < 21) ? 9 : 8;
    int c = cgrp;
    SETBB(c);
    LOADBG(bgA, 0);
    for (int ct = 0; ct < nct; ++ct) {
        LOADBG(bgB, 1);  MFMA64(0, bgA);
        LOADBG(bgA, 2);  MFMA64(1, bgB);
        LOADBG(bgB, 3);  MFMA64(2, bgA);
        if (ct < nct - 1) { SETBB(c + 32); LOADBG(bgA, 0); }
        MFMA64(3, bgB);

        // ---- per-tile epilogue (also hides next-tile kb0 load latency)
        {
            const float CLIPC = 0.99999950f;  // cos(0.001)
            const float ISCL  = 1.0f / 256.0f;
            int colbase = c * 256 + wn + fr;
            #pragma unroll
            for (int m = 0; m < 4; ++m) {
                #pragma unroll
                for (int reg = 0; reg < 4; ++reg) {
                    float s = 0.0f;
                    #pragma unroll
                    for (int n = 0; n < 4; ++n) {
                        int col = colbase + n * 16;
                        float cc = acc[m][n][reg] * ISCL;
                        cc = fminf(fmaxf(cc, -CLIPC), CLIPC);
                        float term = __expf(64.0f * cc - 64.0f);
                        s += (col < NCLS) ? term : 0.0f;
                    }
                    s += __shfl_xor(s, 1); s += __shfl_xor(s, 2);
                    s += __shfl_xor(s, 4); s += __shfl_xor(s, 8);
                    if (fr == 0) atomicAdd(&red[wm + m * 16 + fq * 4 + reg], s);
                }
            }
            #pragma unroll
            for (int m = 0; m < 4; ++m)
                #pragma unroll
                for (int n = 0; n < 4; ++n)
                    acc[m][n] = vzero;
        }
        c += 32;
    }
#undef SETBB
#undef LOADBG
#undef MFMA64

    __syncthreads();
    if (tid < 128) atomicAdd(rowsum + mgrp * 128 + tid, red[tid]);
    __syncthreads();                 // drains each thread's atomics (vmcnt)
    if (tid == 0) {
        __threadfence();             // device-scope: rowsum visible before count
        int old = atomicAdd(done, 1);
        lastBlk = (old == 255);
    }
    __syncthreads();
    if (!lastBlk) return;

    // ---- fused finalize (last block, 512 thr; rows tid and tid+512) --------
    float v0 = fminf(fmaxf(rownorm[tid],       0.001f), 100.0f);
    float v1 = fminf(fmaxf(rownorm[tid + 512], 0.001f), 100.0f);
    float s = wave_reduce_sum(v0 + v1);
    if (lane == 0) fpart[wv] = s;
    __syncthreads();
    if (tid < 64) {
        float p = (lane < 8) ? fpart[lane] : 0.0f;
        p = wave_reduce_sum(p);
        if (lane == 0) fbc[0] = p * (1.0f / 1024.0f);
    }
    __syncthreads();
    float mean = fbc[0];
    float d0 = v0 - mean, d1 = v1 - mean;
    s = wave_reduce_sum(d0 * d0 + d1 * d1);
    if (lane == 0) fpart[wv] = s;
    __syncthreads();
    if (tid < 64) {
        float p = (lane < 8) ? fpart[lane] : 0.0f;
        p = wave_reduce_sum(p);
        if (lane == 0) fbc[1] = sqrtf(p * (1.0f / 1023.0f));  // ddof=1
    }
    __syncthreads();
    float stdv = fbc[1];

    const float CLIPC = 0.99999950f;
    const float PI = 3.14159265358979323846f;
    float lsum = 0.0f;
    #pragma unroll
    for (int h = 0; h < 2; ++h) {
        int r = tid + h * 512;
        float d = (h == 0) ? d0 : d1;
        float ms = d / (stdv + 0.001f) * 0.333f;
        ms = fminf(fmaxf(ms, -1.0f), 1.0f);
        float g_ang = -0.4f * ms;
        float g_add =  0.4f + 0.4f * ms;
        float cl  = fminf(fmaxf(coslab[r], -1.0f), 1.0f);
        float cne = fminf(fmaxf(cl, -CLIPC), CLIPC);
        float logit_non = 64.0f * cne;
        float theta = acosf(cl);
        float tm = fminf(fmaxf(theta + g_ang, 0.001f), PI - 0.001f);
        float logit_true = (__cosf(tm) - g_add) * 64.0f;
        float rs = __hip_atomic_load(&rowsum[r], __ATOMIC_RELAXED,
                                     __HIP_MEMORY_SCOPE_AGENT);
        float ssum = rs - __expf(logit_non - 64.0f) + __expf(logit_true - 64.0f);
        lsum += logf(ssum) + 64.0f - logit_true;
    }
    s = wave_reduce_sum(lsum);
    if (lane == 0) fpart[wv] = s;
    __syncthreads();
    if (tid < 64) {
        float p = (lane < 8) ? fpart[lane] : 0.0f;
        p = wave_reduce_sum(p);
        if (lane == 0) out[0] = p * (1.0f / 1024.0f);
    }
}

extern "C" void kernel_launch(void* const* d_in, const int* in_sizes, int n_in,
                              void* d_out, int out_size, void* d_ws, size_t ws_size,
                              hipStream_t stream) {
    const float* x      = (const float*)d_in[0];
    const int*   labels = (const int*)d_in[1];
    const float* W      = (const float*)d_in[2];
    float* out = (float*)d_out;
    char* ws = (char*)d_ws;

    // workspace layout (~36.75 MB)
    const size_t SZ_WT = (size_t)NC16 * 8192;   // transposed W fp8
    const size_t SZ_AN = 524288;                // 1024*512 fp8 (transposed)
    uint8_t* WT  = (uint8_t*)ws;
    uint8_t* AnT = (uint8_t*)(ws + SZ_WT);
    float* rownorm = (float*)(ws + SZ_WT + SZ_AN);
    float* rowsum  = rownorm + 1024;
    float* coslab  = rowsum + 1024;
    int*   done    = (int*)(coslab + 1024);

    prep_kernel<<<NROWS / 4 + NC16, 256, 0, stream>>>(
        x, W, labels, AnT, WT, rownorm, coslab, rowsum, done);
    gemm8_kernel<<<256, 512, 0, stream>>>(
        AnT, WT, rowsum, coslab, rownorm, out, done);
}

// Round 8
// 298.421 us; speedup vs baseline: 1.2520x; 1.2520x over previous
//
#include <hip/hip_runtime.h>
#include <hip/hip_bf16.h>
#include <stdint.h>

#define DIM 512
#define NROWS 1024
#define NCLS 70722
#define NC16 4421                   // ceil(70722/16) 16-class groups
// 277 c-tiles of 256 cols; 32 c-groups: cgrp<21 own 9 tiles, else 8 (stride-32)

typedef float floatx4 __attribute__((ext_vector_type(4)));

// pack 4 floats -> 4 OCP e4m3 bytes (HW cvt, RNE+sat)
__device__ __forceinline__ unsigned pk4_fp8(float a, float b, float c, float d) {
    unsigned v = 0;
    v = __builtin_amdgcn_cvt_pk_fp8_f32(a, b, v, false);  // low 16 bits
    v = __builtin_amdgcn_cvt_pk_fp8_f32(c, d, v, true);   // high 16 bits
    return v;
}

__device__ __forceinline__ float wave_reduce_sum(float s) {
    #pragma unroll
    for (int m = 1; m < 64; m <<= 1) s += __shfl_xor(s, m);
    return s;
}

// --- kernel 1: fused prep, fragment-transposed outputs (R7, proven) ----------
// WT layout: 8B k-slot j of class r: WT[(r>>4)*8192 + j*128 + (r&15)*8].
__global__ __launch_bounds__(256) void prep_kernel(
        const float* __restrict__ x, const float* __restrict__ W,
        const int* __restrict__ labels,
        uint8_t* __restrict__ AnT, uint8_t* __restrict__ WT,
        float* __restrict__ rownorm, float* __restrict__ coslab,
        float* __restrict__ rowsum, int* __restrict__ done) {
    __shared__ uint8_t lds[16 * 520];   // 520B row stride: conflict-free transpose
    int b = blockIdx.x;
    int wv = threadIdx.x >> 6, lane = threadIdx.x & 63;
    if (b < NROWS / 4) {
        if (b == 0 && threadIdx.x == 0) *done = 0;
        if (threadIdx.x < 4) rowsum[b * 4 + threadIdx.x] = 0.0f;
        int row = b * 4 + wv;
        int lab = labels[row];
        const float4* xs = (const float4*)(x + (size_t)row * DIM);
        const float4* ws = (const float4*)(W + (size_t)lab * DIM);
        float4 xa = xs[lane * 2], xb = xs[lane * 2 + 1];
        float4 wa = ws[lane * 2], wb = ws[lane * 2 + 1];
        float dxx = xa.x*xa.x + xa.y*xa.y + xa.z*xa.z + xa.w*xa.w
                  + xb.x*xb.x + xb.y*xb.y + xb.z*xb.z + xb.w*xb.w;
        float dww = wa.x*wa.x + wa.y*wa.y + wa.z*wa.z + wa.w*wa.w
                  + wb.x*wb.x + wb.y*wb.y + wb.z*wb.z + wb.w*wb.w;
        float dxw = xa.x*wa.x + xa.y*wa.y + xa.z*wa.z + xa.w*wa.w
                  + xb.x*wb.x + xb.y*wb.y + xb.z*wb.z + xb.w*wb.w;
        dxx = wave_reduce_sum(dxx);
        dww = wave_reduce_sum(dww);
        dxw = wave_reduce_sum(dxw);
        float norm = sqrtf(dxx);
        float s16 = 16.0f / fmaxf(norm, 1e-12f);
        uint2 p;
        p.x = pk4_fp8(xa.x*s16, xa.y*s16, xa.z*s16, xa.w*s16);
        p.y = pk4_fp8(xb.x*s16, xb.y*s16, xb.z*s16, xb.w*s16);
        *(uint2*)(AnT + (size_t)(row >> 4) * 8192 + lane * 128 + (row & 15) * 8) = p;
        if (lane == 0) {
            rownorm[row] = norm;
            coslab[row]  = dxw / (fmaxf(norm, 1e-12f) * fmaxf(sqrtf(dww), 1e-12f));
        }
    } else {
        int g = b - NROWS / 4;              // 16-class group
        float4 va[4], vb[4];
        #pragma unroll
        for (int j = 0; j < 4; ++j) {
            int c = g * 16 + wv * 4 + j;
            va[j] = make_float4(0.f, 0.f, 0.f, 0.f);
            vb[j] = make_float4(0.f, 0.f, 0.f, 0.f);
            if (c < NCLS) {
                const float4* src = (const float4*)(W + (size_t)c * DIM);
                va[j] = src[lane * 2]; vb[j] = src[lane * 2 + 1];
            }
        }
        #pragma unroll
        for (int j = 0; j < 4; ++j) {
            float ss = va[j].x*va[j].x + va[j].y*va[j].y + va[j].z*va[j].z + va[j].w*va[j].w
                     + vb[j].x*vb[j].x + vb[j].y*vb[j].y + vb[j].z*vb[j].z + vb[j].w*vb[j].w;
            ss = wave_reduce_sum(ss);
            float s16 = 16.0f / fmaxf(sqrtf(ss), 1e-12f);
            uint2 p;
            p.x = pk4_fp8(va[j].x*s16, va[j].y*s16, va[j].z*s16, va[j].w*s16);
            p.y = pk4_fp8(vb[j].x*s16, vb[j].y*s16, vb[j].z*s16, vb[j].w*s16);
            int r = wv * 4 + j;
            *(uint2*)(&lds[r * 520 + lane * 8]) = p;
        }
        __syncthreads();
        // transposed burst: thread t writes out bytes [32t,32t+32) of the 8KB
        // group; out byte 8v maps to (j=v>>4, r=v&15) = lds[r*520 + j*8]
        int t = threadIdx.x;
        uint2 v0 = *(const uint2*)&lds[((4*t+0) & 15) * 520 + ((4*t+0) >> 4) * 8];
        uint2 v1 = *(const uint2*)&lds[((4*t+1) & 15) * 520 + ((4*t+1) >> 4) * 8];
        uint2 v2 = *(const uint2*)&lds[((4*t+2) & 15) * 520 + ((4*t+2) >> 4) * 8];
        uint2 v3 = *(const uint2*)&lds[((4*t+3) & 15) * 520 + ((4*t+3) >> 4) * 8];
        uint4 q0, q1;
        q0.x = v0.x; q0.y = v0.y; q0.z = v1.x; q0.w = v1.y;
        q1.x = v2.x; q1.y = v2.y; q1.z = v3.x; q1.w = v3.y;
        uint8_t* dst = WT + (size_t)g * 8192 + t * 32;
        *(uint4*)dst        = q0;
        *(uint4*)(dst + 16) = q1;
    }
}

// --- kernel 2: zero-LDS register GEMM, HALF-KB depth-1 pipeline --------------
// 256 blocks (8 mgrp x 32 cgrp), 512 thr, wave = 64M x 64C. A fragments for
// ALL of K register-resident (af[4][16]). bg double-buffered at HALF-kb
// granularity: bgA[4][2]/bgB[4][2] = 32 VGPR total (same footprint as R5's
// non-spilling single buffer). 8 loads of half h+1 overlap 32 MFMA of half h;
// next c-tile's half 0 prefetched under the epilogue. Fused finalize.
__global__ __launch_bounds__(512, 2) void gemm8_kernel(
        const uint8_t* __restrict__ AnT, const uint8_t* __restrict__ WT,
        float* __restrict__ rowsum, const float* __restrict__ coslab,
        const float* __restrict__ rownorm, float* __restrict__ out,
        int* __restrict__ done) {
    __shared__ float red[128];
    __shared__ float fpart[8];
    __shared__ float fbc[2];
    __shared__ int lastBlk;
    int b = blockIdx.x;
    int mgrp = b >> 5, cgrp = b & 31;
    int tid = threadIdx.x, lane = tid & 63, wv = tid >> 6;

    int wm = (wv >> 2) * 64, wn = (wv & 3) * 64;   // wave = 64M x 64C
    int fr = lane & 15, fq = lane >> 4;

    // ---- A fragments for all of K: 64 coalesced 512B wave-loads
    long af[4][16];
    const uint8_t* ab = AnT + (size_t)(mgrp * 8 + (wm >> 4)) * 8192 + fq * 128 + fr * 8;
    #pragma unroll
    for (int m = 0; m < 4; ++m)
        #pragma unroll
        for (int ksl = 0; ksl < 16; ++ksl)
            af[m][ksl] = *(const long*)(ab + m * 8192 + ksl * 512);

    if (tid < 128) red[tid] = 0.0f;
    __syncthreads();

    const floatx4 vzero = {0.0f, 0.0f, 0.0f, 0.0f};
    floatx4 acc[4][4] = {};
    long bgA[4][2], bgB[4][2];
    const uint8_t* bb[4];

#define SETBB(cc) do { \
        _Pragma("unroll") \
        for (int n = 0; n < 4; ++n) { \
            int g = min((cc) * 16 + (wn >> 4) + n, NC16 - 1); \
            bb[n] = WT + (size_t)g * 8192 + fq * 128 + fr * 8; \
        } } while (0)

// load half hh (1KB = 2 k-slices) into BG: 8 x dwordx2
#define LOADH(BG, hh) do { \
        _Pragma("unroll") \
        for (int n = 0; n < 4; ++n) { \
            BG[n][0] = *(const long*)(bb[n] + (hh) * 1024); \
            BG[n][1] = *(const long*)(bb[n] + (hh) * 1024 + 512); \
        } } while (0)

// 32 MFMA consuming half hh from BG
#define MFMA32(BG, hh) do { \
        __builtin_amdgcn_s_setprio(1); \
        _Pragma("unroll") \
        for (int ks = 0; ks < 2; ++ks) \
            _Pragma("unroll") \
            for (int m = 0; m < 4; ++m) \
                _Pragma("unroll") \
                for (int n = 0; n < 4; ++n) \
                    acc[m][n] = __builtin_amdgcn_mfma_f32_16x16x32_fp8_fp8( \
                        af[m][(hh) * 2 + ks], BG[n][ks], acc[m][n], 0, 0, 0); \
        __builtin_amdgcn_s_setprio(0); \
    } while (0)

    int nct = (cgrp < 21) ? 9 : 8;
    int c = cgrp;
    SETBB(c);
    LOADH(bgA, 0);
    for (int ct = 0; ct < nct; ++ct) {
        LOADH(bgB, 1);  MFMA32(bgA, 0);
        LOADH(bgA, 2);  MFMA32(bgB, 1);
        LOADH(bgB, 3);  MFMA32(bgA, 2);
        LOADH(bgA, 4);  MFMA32(bgB, 3);
        LOADH(bgB, 5);  MFMA32(bgA, 4);
        LOADH(bgA, 6);  MFMA32(bgB, 5);
        LOADH(bgB, 7);  MFMA32(bgA, 6);
        if (ct < nct - 1) { SETBB(c + 32); LOADH(bgA, 0); }
        MFMA32(bgB, 7);

        // ---- per-tile epilogue (also hides next-tile half-0 load latency)
        {
            const float CLIPC = 0.99999950f;  // cos(0.001)
            const float ISCL  = 1.0f / 256.0f;
            int colbase = c * 256 + wn + fr;
            #pragma unroll
            for (int m = 0; m < 4; ++m) {
                #pragma unroll
                for (int reg = 0; reg < 4; ++reg) {
                    float s = 0.0f;
                    #pragma unroll
                    for (int n = 0; n < 4; ++n) {
                        int col = colbase + n * 16;
                        float cc = acc[m][n][reg] * ISCL;
                        cc = fminf(fmaxf(cc, -CLIPC), CLIPC);
                        float term = __expf(64.0f * cc - 64.0f);
                        s += (col < NCLS) ? term : 0.0f;
                    }
                    s += __shfl_xor(s, 1); s += __shfl_xor(s, 2);
                    s += __shfl_xor(s, 4); s += __shfl_xor(s, 8);
                    if (fr == 0) atomicAdd(&red[wm + m * 16 + fq * 4 + reg], s);
                }
            }
            #pragma unroll
            for (int m = 0; m < 4; ++m)
                #pragma unroll
                for (int n = 0; n < 4; ++n)
                    acc[m][n] = vzero;
        }
        c += 32;
    }
#undef SETBB
#undef LOADH
#undef MFMA32

    __syncthreads();
    if (tid < 128) atomicAdd(rowsum + mgrp * 128 + tid, red[tid]);
    __syncthreads();                 // drains each thread's atomics
    if (tid == 0) {
        __threadfence();             // device-scope: rowsum visible before count
        int old = atomicAdd(done, 1);
        lastBlk = (old == 255);
    }
    __syncthreads();
    if (!lastBlk) return;

    // ---- fused finalize (last block, 512 thr; rows tid and tid+512) --------
    float v0 = fminf(fmaxf(rownorm[tid],       0.001f), 100.0f);
    float v1 = fminf(fmaxf(rownorm[tid + 512], 0.001f), 100.0f);
    float s = wave_reduce_sum(v0 + v1);
    if (lane == 0) fpart[wv] = s;
    __syncthreads();
    if (tid < 64) {
        float p = (lane < 8) ? fpart[lane] : 0.0f;
        p = wave_reduce_sum(p);
        if (lane == 0) fbc[0] = p * (1.0f / 1024.0f);
    }
    __syncthreads();
    float mean = fbc[0];
    float d0 = v0 - mean, d1 = v1 - mean;
    s = wave_reduce_sum(d0 * d0 + d1 * d1);
    if (lane == 0) fpart[wv] = s;
    __syncthreads();
    if (tid < 64) {
        float p = (lane < 8) ? fpart[lane] : 0.0f;
        p = wave_reduce_sum(p);
        if (lane == 0) fbc[1] = sqrtf(p * (1.0f / 1023.0f));  // ddof=1
    }
    __syncthreads();
    float stdv = fbc[1];

    const float CLIPC = 0.99999950f;
    const float PI = 3.14159265358979323846f;
    float lsum = 0.0f;
    #pragma unroll
    for (int h = 0; h < 2; ++h) {
        int r = tid + h * 512;
        float d = (h == 0) ? d0 : d1;
        float ms = d / (stdv + 0.001f) * 0.333f;
        ms = fminf(fmaxf(ms, -1.0f), 1.0f);
        float g_ang = -0.4f * ms;
        float g_add =  0.4f + 0.4f * ms;
        float cl  = fminf(fmaxf(coslab[r], -1.0f), 1.0f);
        float cne = fminf(fmaxf(cl, -CLIPC), CLIPC);
        float logit_non = 64.0f * cne;
        float theta = acosf(cl);
        float tm = fminf(fmaxf(theta + g_ang, 0.001f), PI - 0.001f);
        float logit_true = (__cosf(tm) - g_add) * 64.0f;
        float rs = __hip_atomic_load(&rowsum[r], __ATOMIC_RELAXED,
                                     __HIP_MEMORY_SCOPE_AGENT);
        float ssum = rs - __expf(logit_non - 64.0f) + __expf(logit_true - 64.0f);
        lsum += logf(ssum) + 64.0f - logit_true;
    }
    s = wave_reduce_sum(lsum);
    if (lane == 0) fpart[wv] = s;
    __syncthreads();
    if (tid < 64) {
        float p = (lane < 8) ? fpart[lane] : 0.0f;
        p = wave_reduce_sum(p);
        if (lane == 0) out[0] = p * (1.0f / 1024.0f);
    }
}

extern "C" void kernel_launch(void* const* d_in, const int* in_sizes, int n_in,
                              void* d_out, int out_size, void* d_ws, size_t ws_size,
                              hipStream_t stream) {
    const float* x      = (const float*)d_in[0];
    const int*   labels = (const int*)d_in[1];
    const float* W      = (const float*)d_in[2];
    float* out = (float*)d_out;
    char* ws = (char*)d_ws;

    // workspace layout (~36.75 MB)
    const size_t SZ_WT = (size_t)NC16 * 8192;   // transposed W fp8
    const size_t SZ_AN = 524288;                // 1024*512 fp8 (transposed)
    uint8_t* WT  = (uint8_t*)ws;
    uint8_t* AnT = (uint8_t*)(ws + SZ_WT);
    float* rownorm = (float*)(ws + SZ_WT + SZ_AN);
    float* rowsum  = rownorm + 1024;
    float* coslab  = rowsum + 1024;
    int*   done    = (int*)(coslab + 1024);

    prep_kernel<<<NROWS / 4 + NC16, 256, 0, stream>>>(
        x, W, labels, AnT, WT, rownorm, coslab, rowsum, done);
    gemm8_kernel<<<256, 512, 0, stream>>>(
        AnT, WT, rowsum, coslab, rownorm, out, done);
}

// Round 9
// 289.405 us; speedup vs baseline: 1.2910x; 1.0312x over previous
//
#include <hip/hip_runtime.h>
#include <hip/hip_bf16.h>
#include <stdint.h>

#define DIM 512
#define NROWS 1024
#define NCLS 70722
#define NC16 4421                   // ceil(70722/16) 16-class groups
// 277 c-tiles of 256 cols; 32 c-groups: cgrp<21 own 9 tiles, else 8 (stride-32)

typedef float floatx4 __attribute__((ext_vector_type(4)));

// pack 4 floats -> 4 OCP e4m3 bytes (HW cvt, RNE+sat)
__device__ __forceinline__ unsigned pk4_fp8(float a, float b, float c, float d) {
    unsigned v = 0;
    v = __builtin_amdgcn_cvt_pk_fp8_f32(a, b, v, false);  // low 16 bits
    v = __builtin_amdgcn_cvt_pk_fp8_f32(c, d, v, true);   // high 16 bits
    return v;
}

__device__ __forceinline__ float wave_reduce_sum(float s) {
    #pragma unroll
    for (int m = 1; m < 64; m <<= 1) s += __shfl_xor(s, m);
    return s;
}

// --- kernel 1: fused prep, fragment-transposed outputs -----------------------
// WT layout: 8B k-slot j of class r: WT[(r>>4)*8192 + j*128 + (r&15)*8].
// blocks [0,256):  x rows (wave-per-row) -> AnT, rownorm, coslab, rowsum=0;
//                  block 0 zeroes the done counter.
// blocks [256,..): one 16-class group per block; 16-lane group per row
//                  (4 rows/wave in parallel, 4-level reduce) -> LDS tile ->
//                  one coalesced 8KB transposed burst.
__global__ __launch_bounds__(256) void prep_kernel(
        const float* __restrict__ x, const float* __restrict__ W,
        const int* __restrict__ labels,
        uint8_t* __restrict__ AnT, uint8_t* __restrict__ WT,
        float* __restrict__ rownorm, float* __restrict__ coslab,
        float* __restrict__ rowsum, int* __restrict__ done) {
    __shared__ uint8_t lds[16 * 520];   // 520B row stride
    int b = blockIdx.x;
    int wv = threadIdx.x >> 6, lane = threadIdx.x & 63;
    if (b < NROWS / 4) {
        if (b == 0 && threadIdx.x == 0) *done = 0;
        if (threadIdx.x < 4) rowsum[b * 4 + threadIdx.x] = 0.0f;
        int row = b * 4 + wv;
        int lab = labels[row];
        const float4* xs = (const float4*)(x + (size_t)row * DIM);
        const float4* ws = (const float4*)(W + (size_t)lab * DIM);
        float4 xa = xs[lane * 2], xb = xs[lane * 2 + 1];
        float4 wa = ws[lane * 2], wb = ws[lane * 2 + 1];
        float dxx = xa.x*xa.x + xa.y*xa.y + xa.z*xa.z + xa.w*xa.w
                  + xb.x*xb.x + xb.y*xb.y + xb.z*xb.z + xb.w*xb.w;
        float dww = wa.x*wa.x + wa.y*wa.y + wa.z*wa.z + wa.w*wa.w
                  + wb.x*wb.x + wb.y*wb.y + wb.z*wb.z + wb.w*wb.w;
        float dxw = xa.x*wa.x + xa.y*wa.y + xa.z*wa.z + xa.w*wa.w
                  + xb.x*wb.x + xb.y*wb.y + xb.z*wb.z + xb.w*wb.w;
        dxx = wave_reduce_sum(dxx);
        dww = wave_reduce_sum(dww);
        dxw = wave_reduce_sum(dxw);
        float norm = sqrtf(dxx);
        float s16 = 16.0f / fmaxf(norm, 1e-12f);
        uint2 p;
        p.x = pk4_fp8(xa.x*s16, xa.y*s16, xa.z*s16, xa.w*s16);
        p.y = pk4_fp8(xb.x*s16, xb.y*s16, xb.z*s16, xb.w*s16);
        *(uint2*)(AnT + (size_t)(row >> 4) * 8192 + lane * 128 + (row & 15) * 8) = p;
        if (lane == 0) {
            rownorm[row] = norm;
            coslab[row]  = dxw / (fmaxf(norm, 1e-12f) * fmaxf(sqrtf(dww), 1e-12f));
        }
    } else {
        int g = b - NROWS / 4;              // 16-class group
        int sub = lane & 15, grp = lane >> 4;
        int r = wv * 4 + grp;               // row within group, 0..15
        int c = g * 16 + r;
        // 16 lanes per row: lane covers floats [32*sub, 32*sub+32)
        const float4* src = (const float4*)(W + (size_t)min(c, NCLS - 1) * DIM);
        float4 v[8];
        #pragma unroll
        for (int i = 0; i < 8; ++i) v[i] = src[sub * 8 + i];
        if (c >= NCLS) {
            #pragma unroll
            for (int i = 0; i < 8; ++i) v[i] = make_float4(0.f, 0.f, 0.f, 0.f);
        }
        float ss = 0.0f;
        #pragma unroll
        for (int i = 0; i < 8; ++i)
            ss += v[i].x*v[i].x + v[i].y*v[i].y + v[i].z*v[i].z + v[i].w*v[i].w;
        ss += __shfl_xor(ss, 1); ss += __shfl_xor(ss, 2);
        ss += __shfl_xor(ss, 4); ss += __shfl_xor(ss, 8);   // within 16-lane group
        float s16 = 16.0f / fmaxf(sqrtf(ss), 1e-12f);
        // lane owns 8B k-slots j = 4*sub+k, k=0..3 of row r
        #pragma unroll
        for (int k = 0; k < 4; ++k) {
            uint2 p;
            p.x = pk4_fp8(v[2*k].x*s16,   v[2*k].y*s16,   v[2*k].z*s16,   v[2*k].w*s16);
            p.y = pk4_fp8(v[2*k+1].x*s16, v[2*k+1].y*s16, v[2*k+1].z*s16, v[2*k+1].w*s16);
            *(uint2*)(&lds[r * 520 + (4 * sub + k) * 8]) = p;
        }
        __syncthreads();
        // transposed burst: thread t writes out bytes [32t,32t+32) of the 8KB
        // group; out 8B-unit v maps to (j=v>>4, r=v&15) = lds[r*520 + j*8]
        int t = threadIdx.x;
        uint2 v0 = *(const uint2*)&lds[((4*t+0) & 15) * 520 + ((4*t+0) >> 4) * 8];
        uint2 v1 = *(const uint2*)&lds[((4*t+1) & 15) * 520 + ((4*t+1) >> 4) * 8];
        uint2 v2 = *(const uint2*)&lds[((4*t+2) & 15) * 520 + ((4*t+2) >> 4) * 8];
        uint2 v3 = *(const uint2*)&lds[((4*t+3) & 15) * 520 + ((4*t+3) >> 4) * 8];
        uint4 q0, q1;
        q0.x = v0.x; q0.y = v0.y; q0.z = v1.x; q0.w = v1.y;
        q1.x = v2.x; q1.y = v2.y; q1.z = v3.x; q1.w = v3.y;
        uint8_t* dst = WT + (size_t)g * 8192 + t * 32;
        *(uint4*)dst        = q0;
        *(uint4*)(dst + 16) = q1;
    }
}

// --- kernel 2: zero-LDS register GEMM (R5 loop, measured <=83us) + finalize --
// 256 blocks (8 mgrp x 32 cgrp), 512 thr, wave = 64M x 64C. A fragments for
// ALL of K register-resident (af[4][16]). Per kb: single bg[4][4] loaded
// right before its 64-MFMA cluster -- NO explicit cross-phase pipeline; the
// barrier-free loop lets the compiler hoist loads (R7/R8 SSA attempts both
// regressed via spill/schedule-pinning). Fused last-block finalize.
__global__ __launch_bounds__(512) void gemm8_kernel(
        const uint8_t* __restrict__ AnT, const uint8_t* __restrict__ WT,
        float* __restrict__ rowsum, const float* __restrict__ coslab,
        const float* __restrict__ rownorm, float* __restrict__ out,
        int* __restrict__ done) {
    __shared__ float red[128];
    __shared__ float fpart[8];
    __shared__ float fbc[2];
    __shared__ int lastBlk;
    int b = blockIdx.x;
    int mgrp = b >> 5, cgrp = b & 31;
    int tid = threadIdx.x, lane = tid & 63, wv = tid >> 6;

    int wm = (wv >> 2) * 64, wn = (wv & 3) * 64;   // wave = 64M x 64C
    int fr = lane & 15, fq = lane >> 4;

    // ---- A fragments for all of K: 64 coalesced 512B wave-loads
    long af[4][16];
    const uint8_t* ab = AnT + (size_t)(mgrp * 8 + (wm >> 4)) * 8192 + fq * 128 + fr * 8;
    #pragma unroll
    for (int m = 0; m < 4; ++m)
        #pragma unroll
        for (int ksl = 0; ksl < 16; ++ksl)
            af[m][ksl] = *(const long*)(ab + m * 8192 + ksl * 512);

    if (tid < 128) red[tid] = 0.0f;
    __syncthreads();

    const floatx4 vzero = {0.0f, 0.0f, 0.0f, 0.0f};
    floatx4 acc[4][4] = {};

    int nct = (cgrp < 21) ? 9 : 8;
    int c = cgrp;
    for (int ct = 0; ct < nct; ++ct) {
        // per-thread B fragment base pointers (4 cols owned: n=0..3)
        const uint8_t* bb[4];
        #pragma unroll
        for (int n = 0; n < 4; ++n) {
            int g = min(c * 16 + (wn >> 4) + n, NC16 - 1);  // clamp: masked below
            bb[n] = WT + (size_t)g * 8192 + fq * 128 + fr * 8;
        }
        #pragma unroll
        for (int kb = 0; kb < 4; ++kb) {
            long bg[4][4];
            #pragma unroll
            for (int n = 0; n < 4; ++n)
                #pragma unroll
                for (int ks = 0; ks < 4; ++ks)
                    bg[n][ks] = *(const long*)(bb[n] + kb * 2048 + ks * 512);
            __builtin_amdgcn_s_setprio(1);
            #pragma unroll
            for (int ks = 0; ks < 4; ++ks)
                #pragma unroll
                for (int m = 0; m < 4; ++m)
                    #pragma unroll
                    for (int n = 0; n < 4; ++n)
                        acc[m][n] = __builtin_amdgcn_mfma_f32_16x16x32_fp8_fp8(
                            af[m][kb * 4 + ks], bg[n][ks], acc[m][n], 0, 0, 0);
            __builtin_amdgcn_s_setprio(0);
        }

        // ---- per-tile epilogue: cosine = acc/256; exp(64c-64); reduce
        {
            const float CLIPC = 0.99999950f;  // cos(0.001)
            const float ISCL  = 1.0f / 256.0f;
            int colbase = c * 256 + wn + fr;
            #pragma unroll
            for (int m = 0; m < 4; ++m) {
                #pragma unroll
                for (int reg = 0; reg < 4; ++reg) {
                    float s = 0.0f;
                    #pragma unroll
                    for (int n = 0; n < 4; ++n) {
                        int col = colbase + n * 16;
                        float cc = acc[m][n][reg] * ISCL;
                        cc = fminf(fmaxf(cc, -CLIPC), CLIPC);
                        float term = __expf(64.0f * cc - 64.0f);
                        s += (col < NCLS) ? term : 0.0f;
                    }
                    s += __shfl_xor(s, 1); s += __shfl_xor(s, 2);
                    s += __shfl_xor(s, 4); s += __shfl_xor(s, 8);
                    if (fr == 0) atomicAdd(&red[wm + m * 16 + fq * 4 + reg], s);
                }
            }
            #pragma unroll
            for (int m = 0; m < 4; ++m)
                #pragma unroll
                for (int n = 0; n < 4; ++n)
                    acc[m][n] = vzero;
        }
        c += 32;
    }

    __syncthreads();
    if (tid < 128) atomicAdd(rowsum + mgrp * 128 + tid, red[tid]);
    __syncthreads();                 // drains each thread's atomics
    if (tid == 0) {
        __threadfence();             // device-scope: rowsum visible before count
        int old = atomicAdd(done, 1);
        lastBlk = (old == 255);
    }
    __syncthreads();
    if (!lastBlk) return;

    // ---- fused finalize (last block, 512 thr; rows tid and tid+512) --------
    float v0 = fminf(fmaxf(rownorm[tid],       0.001f), 100.0f);
    float v1 = fminf(fmaxf(rownorm[tid + 512], 0.001f), 100.0f);
    float s = wave_reduce_sum(v0 + v1);
    if (lane == 0) fpart[wv] = s;
    __syncthreads();
    if (tid < 64) {
        float p = (lane < 8) ? fpart[lane] : 0.0f;
        p = wave_reduce_sum(p);
        if (lane == 0) fbc[0] = p * (1.0f / 1024.0f);
    }
    __syncthreads();
    float mean = fbc[0];
    float d0 = v0 - mean, d1 = v1 - mean;
    s = wave_reduce_sum(d0 * d0 + d1 * d1);
    if (lane == 0) fpart[wv] = s;
    __syncthreads();
    if (tid < 64) {
        float p = (lane < 8) ? fpart[lane] : 0.0f;
        p = wave_reduce_sum(p);
        if (lane == 0) fbc[1] = sqrtf(p * (1.0f / 1023.0f));  // ddof=1
    }
    __syncthreads();
    float stdv = fbc[1];

    const float CLIPC = 0.99999950f;
    const float PI = 3.14159265358979323846f;
    float lsum = 0.0f;
    #pragma unroll
    for (int h = 0; h < 2; ++h) {
        int r = tid + h * 512;
        float d = (h == 0) ? d0 : d1;
        float ms = d / (stdv + 0.001f) * 0.333f;
        ms = fminf(fmaxf(ms, -1.0f), 1.0f);
        float g_ang = -0.4f * ms;
        float g_add =  0.4f + 0.4f * ms;
        float cl  = fminf(fmaxf(coslab[r], -1.0f), 1.0f);
        float cne = fminf(fmaxf(cl, -CLIPC), CLIPC);
        float logit_non = 64.0f * cne;
        float theta = acosf(cl);
        float tm = fminf(fmaxf(theta + g_ang, 0.001f), PI - 0.001f);
        float logit_true = (__cosf(tm) - g_add) * 64.0f;
        float rs = __hip_atomic_load(&rowsum[r], __ATOMIC_RELAXED,
                                     __HIP_MEMORY_SCOPE_AGENT);
        float ssum = rs - __expf(logit_non - 64.0f) + __expf(logit_true - 64.0f);
        lsum += logf(ssum) + 64.0f - logit_true;
    }
    s = wave_reduce_sum(lsum);
    if (lane == 0) fpart[wv] = s;
    __syncthreads();
    if (tid < 64) {
        float p = (lane < 8) ? fpart[lane] : 0.0f;
        p = wave_reduce_sum(p);
        if (lane == 0) out[0] = p * (1.0f / 1024.0f);
    }
}

extern "C" void kernel_launch(void* const* d_in, const int* in_sizes, int n_in,
                              void* d_out, int out_size, void* d_ws, size_t ws_size,
                              hipStream_t stream) {
    const float* x      = (const float*)d_in[0];
    const int*   labels = (const int*)d_in[1];
    const float* W      = (const float*)d_in[2];
    float* out = (float*)d_out;
    char* ws = (char*)d_ws;

    // workspace layout (~36.75 MB)
    const size_t SZ_WT = (size_t)NC16 * 8192;   // transposed W fp8
    const size_t SZ_AN = 524288;                // 1024*512 fp8 (transposed)
    uint8_t* WT  = (uint8_t*)ws;
    uint8_t* AnT = (uint8_t*)(ws + SZ_WT);
    float* rownorm = (float*)(ws + SZ_WT + SZ_AN);
    float* rowsum  = rownorm + 1024;
    float* coslab  = rowsum + 1024;
    int*   done    = (int*)(coslab + 1024);

    prep_kernel<<<NROWS / 4 + NC16, 256, 0, stream>>>(
        x, W, labels, AnT, WT, rownorm, coslab, rowsum, done);
    gemm8_kernel<<<256, 512, 0, stream>>>(
        AnT, WT, rowsum, coslab, rownorm, out, done);
}